// Round 6
// baseline (21.653 us; speedup 1.0000x reference)
//
#include <hip/hip_runtime.h>

// (B, S, H) = (8, 2048, 1024), fp32.
// Degenerate math: scores == 1/S exactly (softmax of a constant vector);
// context[b,h] == mean_s enc[b,s,h]; decoder_state cancels entirely.
// Lessons: R2 — grid.sync() ~200us on MI355X; R3 — contended atomics lose;
//          R4 — wide finalize (128 blk) saved 4us; phase A at 16 waves/CU.
// R5: phase A at 32 waves/CU (2048 blocks, chunk=8), partial 8 MiB (L2/L3
//     resident), score-fill folded into A, finalize = pure context reduce.
#define BB 8
#define SS 2048
#define HH 1024
#define NCHUNK 256           // S-chunks per batch
#define CHUNK (SS / NCHUNK)  // 8 rows per block
#define NBLK (BB * NCHUNK)   // 2048 blocks

// Kernel A: block g=(b,c) sums its 8-row chunk; thread t owns float4 column
// h=4t..4t+3 with 8 fully-unrolled independent loads (32 data VGPRs ->
// full 32-waves/CU occupancy at 8 blocks/CU). Also fills 8 scores/block.
__global__ void __launch_bounds__(256)
att_partial_kernel(const float* __restrict__ enc, float* __restrict__ partial,
                   float* __restrict__ out) {
    const int g = blockIdx.x;
    const int b = g >> 8;            // / NCHUNK
    const int c = g & (NCHUNK - 1);
    const int t = threadIdx.x;
    const float4* p =
        (const float4*)(enc + ((size_t)b * SS + (size_t)c * CHUNK) * HH) + t;
    float4 v[CHUNK];
    #pragma unroll
    for (int s = 0; s < CHUNK; ++s) v[s] = p[(size_t)s * (HH / 4)];
    #pragma unroll
    for (int stride = CHUNK / 2; stride > 0; stride >>= 1) {
        #pragma unroll
        for (int s = 0; s < stride; ++s) {
            v[s].x += v[s + stride].x;
            v[s].y += v[s + stride].y;
            v[s].z += v[s + stride].z;
            v[s].w += v[s + stride].w;
        }
    }
    ((float4*)(partial + (size_t)g * HH))[t] = v[0];  // g == b*NCHUNK + c

    // scores: BB*SS = 16384 elems at offset BB*HH; 8 per block.
    if (t < 8) out[BB * HH + g * 8 + t] = 1.0f / SS;
}

// Kernel B: pure context reduce. 128 blocks x 256 threads; block = (b,
// 64-wide h slice); wave cq sums chunks c = cq*64..cq*64+63 (coalesced
// 256 B/wave reads), LDS[4][64] cross-wave combine.
__global__ void __launch_bounds__(256)
att_finalize_kernel(const float* __restrict__ partial, float* __restrict__ out) {
    const int blk = blockIdx.x;        // 0..127
    const int b = blk >> 4;            // / 16
    const int hbase = (blk & 15) * 64;
    const int t = threadIdx.x;
    const int hl = t & 63;
    const int cq = t >> 6;             // 0..3

    const float* p =
        partial + ((size_t)(b * NCHUNK + cq * 64)) * HH + hbase + hl;
    float acc = 0.f;
    #pragma unroll 8
    for (int c = 0; c < 64; ++c) acc += p[(size_t)c * HH];

    __shared__ float lds[4][64];
    lds[cq][hl] = acc;
    __syncthreads();
    if (t < 64) {
        float s = lds[0][t] + lds[1][t] + lds[2][t] + lds[3][t];
        out[b * HH + hbase + t] = s * (1.0f / SS);
    }
}

// Fallback (workspace too small): direct full-column sums.
__global__ void __launch_bounds__(256)
att_direct_kernel(const float* __restrict__ enc, float* __restrict__ out) {
    int tid = blockIdx.x * blockDim.x + threadIdx.x;
    if (tid < BB * HH) {
        int b = tid >> 10;
        int h = tid & (HH - 1);
        const float* p = enc + (size_t)b * SS * HH + h;
        float acc = 0.f;
        for (int s = 0; s < SS; ++s) acc += p[(size_t)s * HH];
        out[tid] = acc * (1.0f / SS);
    } else if (tid < BB * HH + BB * SS) {
        out[tid] = 1.0f / SS;
    }
}

extern "C" void kernel_launch(void* const* d_in, const int* in_sizes, int n_in,
                              void* d_out, int out_size, void* d_ws, size_t ws_size,
                              hipStream_t stream) {
    const float* enc = (const float*)d_in[1];  // encoder_outputs (B,S,H)
    float* out = (float*)d_out;                // [context (B*H) | scores (B*S)]

    const size_t part_bytes = (size_t)NBLK * HH * sizeof(float);  // 8 MiB
    if (d_ws != nullptr && ws_size >= part_bytes) {
        float* partial = (float*)d_ws;
        att_partial_kernel<<<NBLK, 256, 0, stream>>>(enc, partial, out);
        att_finalize_kernel<<<128, 256, 0, stream>>>(partial, out);
    } else {
        const int total_out = BB * HH + BB * SS;
        att_direct_kernel<<<(total_out + 255) / 256, 256, 0, stream>>>(enc, out);
    }
}

// Round 7
// 19.061 us; speedup vs baseline: 1.1360x; 1.1360x over previous
//
#include <hip/hip_runtime.h>

// (B, S, H) = (8, 2048, 1024), fp32.
// Degenerate math: scores == 1/S exactly (softmax of a constant vector);
// context[b,h] == mean_s enc[b,s,h]; decoder_state cancels entirely.
// Lessons: R2 — grid.sync() ~200us on MI355X; R3 — contended atomics lose;
//          R4 — wide finalize (128 blk): 19.5us best; R5 — 2048 blk/8-deep
//          regressed (load depth > occupancy). R6: force 16-deep VMEM issue
//          with sched_group_barrier (compiler was serializing to ~5 deep,
//          evidence: VGPR_Count=32 on the R2 fused kernel).
#define BB 8
#define SS 2048
#define HH 1024
#define NCHUNK 128           // S-chunks per batch
#define CHUNK (SS / NCHUNK)  // 16 rows per block
#define NBLK (BB * NCHUNK)   // 1024 blocks

// Kernel A: block (b,c) sums its 16-row chunk; thread t owns float4 column
// h=4t..4t+3; 16 independent global_load_dwordx4 forced to issue before the
// reduction (sched_group_barrier) -> ~256 B/lane outstanding.
__global__ void __launch_bounds__(256)
att_partial_kernel(const float* __restrict__ enc, float* __restrict__ partial) {
    int blk = blockIdx.x;
    int b = blk >> 7;          // / NCHUNK
    int c = blk & (NCHUNK - 1);
    int t = threadIdx.x;
    const float4* p =
        (const float4*)(enc + ((size_t)b * SS + (size_t)c * CHUNK) * HH) + t;
    float4 v[CHUNK];
    #pragma unroll
    for (int s = 0; s < CHUNK; ++s) v[s] = p[(size_t)s * (HH / 4)];
    // Scheduler directive: emit all 16 VMEM reads first, then the VALU tree.
    __builtin_amdgcn_sched_group_barrier(0x20, 16, 0);  // 16x VMEM_READ
    __builtin_amdgcn_sched_group_barrier(0x02, 64, 0);  // then VALU
    #pragma unroll
    for (int stride = CHUNK / 2; stride > 0; stride >>= 1) {
        #pragma unroll
        for (int s = 0; s < stride; ++s) {
            v[s].x += v[s + stride].x;
            v[s].y += v[s + stride].y;
            v[s].z += v[s + stride].z;
            v[s].w += v[s + stride].w;
        }
    }
    ((float4*)(partial + ((size_t)b * NCHUNK + c) * HH))[t] = v[0];
}

// Kernel B (unchanged from R4): 128 blocks x 256 threads. Block = (b, 64-wide
// h slice). Wave cq sums c = cq*32..cq*32+31 (coalesced 256 B/wave reads),
// LDS[4][64] cross-wave combine; also fills 128 scores per block.
__global__ void __launch_bounds__(256)
att_finalize_kernel(const float* __restrict__ partial, float* __restrict__ out) {
    const int blk = blockIdx.x;        // 0..127
    const int b = blk >> 4;            // / 16
    const int hbase = (blk & 15) * 64;
    const int t = threadIdx.x;
    const int hl = t & 63;
    const int cq = t >> 6;             // 0..3

    const float* p = partial + ((size_t)(b * NCHUNK + cq * 32)) * HH + hbase + hl;
    float acc = 0.f;
    #pragma unroll 8
    for (int c = 0; c < 32; ++c) acc += p[(size_t)c * HH];

    const float inv = 1.0f / SS;
    if (t >= 64 && t < 192) {
        out[BB * HH + blk * 128 + (t - 64)] = inv;
    }

    __shared__ float lds[4][64];
    lds[cq][hl] = acc;
    __syncthreads();
    if (t < 64) {
        float s = lds[0][t] + lds[1][t] + lds[2][t] + lds[3][t];
        out[b * HH + hbase + t] = s * inv;
    }
}

// Fallback (workspace too small): direct full-column sums.
__global__ void __launch_bounds__(256)
att_direct_kernel(const float* __restrict__ enc, float* __restrict__ out) {
    int tid = blockIdx.x * blockDim.x + threadIdx.x;
    if (tid < BB * HH) {
        int b = tid >> 10;
        int h = tid & (HH - 1);
        const float* p = enc + (size_t)b * SS * HH + h;
        float acc = 0.f;
        for (int s = 0; s < SS; ++s) acc += p[(size_t)s * HH];
        out[tid] = acc * (1.0f / SS);
    } else if (tid < BB * HH + BB * SS) {
        out[tid] = 1.0f / SS;
    }
}

extern "C" void kernel_launch(void* const* d_in, const int* in_sizes, int n_in,
                              void* d_out, int out_size, void* d_ws, size_t ws_size,
                              hipStream_t stream) {
    const float* enc = (const float*)d_in[1];  // encoder_outputs (B,S,H)
    float* out = (float*)d_out;                // [context (B*H) | scores (B*S)]

    const size_t part_bytes = (size_t)BB * NCHUNK * HH * sizeof(float);  // 4 MiB
    if (d_ws != nullptr && ws_size >= part_bytes) {
        float* partial = (float*)d_ws;
        att_partial_kernel<<<NBLK, 256, 0, stream>>>(enc, partial);
        att_finalize_kernel<<<128, 256, 0, stream>>>(partial, out);
    } else {
        const int total_out = BB * HH + BB * SS;
        att_direct_kernel<<<(total_out + 255) / 256, 256, 0, stream>>>(enc, out);
    }
}